// Round 2
// baseline (2132.194 us; speedup 1.0000x reference)
//
#include <hip/hip_runtime.h>
#include <math.h>

// Problem constants (B=4, Ci=128, Cg=64, H=W=128), all fp32.
#define BB   4
#define CI   128
#define CG   64
#define CIN  (CI + CG)   // 192
#define HH   128
#define WW   128
#define PP   (HH * WW)   // 16384
#define EPSN 1e-5f

__device__ __forceinline__ int wave_uniform(int x) {
    return __builtin_amdgcn_readfirstlane(x);
}

// ---------------------------------------------------------------------------
// K1: conv11 and conv21 fused (both read input||weight, 3x3 pad1, bias+ReLU).
// Combined output-channel space: gi<4 -> conv11 (y1), gi>=4 -> conv21 (y2).
// Thread = one pixel (64-wide x tiles for coalescing), 32 out-channels/block.
// Weights via wave-uniform s_loads (SGPR operands to v_fma).
// ---------------------------------------------------------------------------
__global__ __launch_bounds__(256) void k_conv_dual(
    const float* __restrict__ input, const float* __restrict__ weight,
    const float* __restrict__ w11, const float* __restrict__ b11,
    const float* __restrict__ w21, const float* __restrict__ b21,
    float* __restrict__ y1, float* __restrict__ y2)
{
    const int t    = threadIdx.x;
    const int tile = blockIdx.x;   // 0..63 : 2 x-tiles x 32 y-tiles (64x4 px)
    const int gi   = blockIdx.y;   // 0..7
    const int b    = blockIdx.z;

    const int tx = (tile & 1) * 64;
    const int ty = (tile >> 1) * 4;
    const int x  = tx + (t & 63);
    const int y  = ty + (t >> 6);

    const float* wsel = (gi < 4) ? w11 : w21;
    const float* bsel = (gi < 4) ? b11 : b21;
    float*       dst  = (gi < 4) ? y1  : y2;
    const int    og   = (gi & 3) * 32;

    float acc[32];
#pragma unroll
    for (int o = 0; o < 32; ++o) acc[o] = bsel[og + o];

    for (int c = 0; c < CIN; ++c) {
        const float* src = (c < CI)
            ? (input  + ((size_t)b * CI + c) * PP)
            : (weight + ((size_t)b * CG + (c - CI)) * PP);
        float r[9];
#pragma unroll
        for (int dy = 0; dy < 3; ++dy) {
            const int  ry  = y + dy - 1;
            const bool oky = ((unsigned)ry < (unsigned)HH);
#pragma unroll
            for (int dx = 0; dx < 3; ++dx) {
                const int  rx = x + dx - 1;
                const bool ok = oky && ((unsigned)rx < (unsigned)WW);
                r[dy * 3 + dx] = ok ? src[ry * WW + rx] : 0.0f;
            }
        }
#pragma unroll
        for (int o = 0; o < 32; ++o) {
            const float* wp = wsel + (((size_t)(og + o)) * CIN + c) * 9;
#pragma unroll
            for (int k = 0; k < 9; ++k) acc[o] = fmaf(wp[k], r[k], acc[o]);
        }
    }

    const size_t obase = ((size_t)b * CI + og) * PP + (size_t)y * WW + x;
#pragma unroll
    for (int o = 0; o < 32; ++o)
        dst[obase + (size_t)o * PP] = fmaxf(acc[o], 0.0f);
}

// ---------------------------------------------------------------------------
// K2: global average pool of y2 -> pooled[b][c]
// ---------------------------------------------------------------------------
__global__ __launch_bounds__(256) void k_pool(
    const float* __restrict__ y2, float* __restrict__ pooled)
{
    const int c = blockIdx.x, b = blockIdx.y, t = threadIdx.x;
    const float* src = y2 + ((size_t)b * CI + c) * PP;
    float s = 0.0f;
    for (int i = t; i < PP; i += 256) s += src[i];
    __shared__ float red[256];
    red[t] = s;
    __syncthreads();
    for (int st = 128; st > 0; st >>= 1) {
        if (t < st) red[t] += red[t + st];
        __syncthreads();
    }
    if (t == 0) pooled[b * CI + c] = red[0] * (1.0f / PP);
}

// ---------------------------------------------------------------------------
// K3: w22o[b][o] = dot(w22[o,:], pooled[b,:]) + b22[o]   (o in [0,16384))
// ---------------------------------------------------------------------------
__global__ __launch_bounds__(256) void k_w22(
    const float* __restrict__ w22, const float* __restrict__ b22,
    const float* __restrict__ pooled, float* __restrict__ w22o)
{
    const int b = blockIdx.y;
    const int o = blockIdx.x * 256 + threadIdx.x;
    __shared__ float pl[CI];
    if (threadIdx.x < CI) pl[threadIdx.x] = pooled[b * CI + threadIdx.x];
    __syncthreads();
    const float4* wr = (const float4*)(w22 + (size_t)o * CI);
    float acc = b22[o];
#pragma unroll 8
    for (int c4 = 0; c4 < CI / 4; ++c4) {
        const float4 w = wr[c4];
        acc += w.x * pl[c4 * 4 + 0] + w.y * pl[c4 * 4 + 1] +
               w.z * pl[c4 * 4 + 2] + w.w * pl[c4 * 4 + 3];
    }
    w22o[(size_t)b * CI * CI + o] = acc;
}

// ---------------------------------------------------------------------------
// K4: fused conv12 (1x1, 128->1152) + guided depthwise 3x3 + BN1 + ReLU.
// Block: 64 pixels (one half-row, y fixed) x 4 channel-groups of 32.
// y1 column block staged in LDS [128][64]; w12/b12/BN via uniform s_loads.
// ---------------------------------------------------------------------------
__global__ __launch_bounds__(256) void k_guided(
    const float* __restrict__ input, const float* __restrict__ y1,
    const float* __restrict__ w12, const float* __restrict__ b12,
    const float* __restrict__ g1, const float* __restrict__ be1,
    const float* __restrict__ m1, const float* __restrict__ v1,
    float* __restrict__ localb)
{
    __shared__ float ly[CI][64];
    const int b  = blockIdx.y;
    const int p0 = blockIdx.x * 64;
    const int t  = threadIdx.x;

    for (int i = t; i < CI * 64; i += 256) {
        const int ch = i >> 6, pp = i & 63;
        ly[ch][pp] = y1[((size_t)b * CI + ch) * PP + p0 + pp];
    }
    __syncthreads();

    const int px  = t & 63;
    const int grp = wave_uniform(t >> 6);   // 0..3, wave-uniform
    const int p   = p0 + px;
    const int y   = p >> 7;
    const int x   = p & 127;

    for (int ci = 0; ci < 32; ++ci) {
        const int cc = grp * 32 + ci;
        float acc9[9];
        const float* bp = b12 + cc * 9;
#pragma unroll
        for (int k = 0; k < 9; ++k) acc9[k] = bp[k];

        for (int cb = 0; cb < CI / 8; ++cb) {
            float yv[8];
#pragma unroll
            for (int j = 0; j < 8; ++j) yv[j] = ly[cb * 8 + j][px];
#pragma unroll
            for (int k = 0; k < 9; ++k) {
                const float* wp = w12 + ((size_t)(cc * 9 + k)) * CI + cb * 8;
#pragma unroll
                for (int j = 0; j < 8; ++j) acc9[k] = fmaf(wp[j], yv[j], acc9[k]);
            }
        }

        // depthwise 3x3 with per-pixel kernel acc9
        const float* src = input + ((size_t)b * CI + cc) * PP;
        float lsum = 0.0f;
#pragma unroll
        for (int dy = 0; dy < 3; ++dy) {
            const int  ry  = y + dy - 1;
            const bool oky = ((unsigned)ry < (unsigned)HH);
#pragma unroll
            for (int dx = 0; dx < 3; ++dx) {
                const int  rx = x + dx - 1;
                const bool ok = oky && ((unsigned)rx < (unsigned)WW);
                const float pv = ok ? src[ry * WW + rx] : 0.0f;
                lsum = fmaf(acc9[dy * 3 + dx], pv, lsum);
            }
        }

        const float scale = g1[cc] / sqrtf(v1[cc] + EPSN);
        const float shift = be1[cc] - m1[cc] * scale;
        localb[((size_t)b * CI + cc) * PP + p] =
            fmaxf(fmaf(lsum, scale, shift), 0.0f);
    }
}

// ---------------------------------------------------------------------------
// K5: channel-mix bmm out[b,i,p] = sum_j w22o[b,i,j]*local[b,j,p], + BN2+ReLU
// ---------------------------------------------------------------------------
__global__ __launch_bounds__(256) void k_bmm(
    const float* __restrict__ localb, const float* __restrict__ w22o,
    const float* __restrict__ g2, const float* __restrict__ be2,
    const float* __restrict__ m2, const float* __restrict__ v2,
    float* __restrict__ out2)
{
    __shared__ float ll[CI][64];
    const int b  = blockIdx.y;
    const int p0 = blockIdx.x * 64;
    const int t  = threadIdx.x;

    for (int i = t; i < CI * 64; i += 256) {
        const int ch = i >> 6, pp = i & 63;
        ll[ch][pp] = localb[((size_t)b * CI + ch) * PP + p0 + pp];
    }
    __syncthreads();

    const int px  = t & 63;
    const int grp = wave_uniform(t >> 6);

    float acc[32];
#pragma unroll
    for (int i = 0; i < 32; ++i) acc[i] = 0.0f;

    for (int jb = 0; jb < CI / 8; ++jb) {
        float yv[8];
#pragma unroll
        for (int j = 0; j < 8; ++j) yv[j] = ll[jb * 8 + j][px];
#pragma unroll
        for (int i = 0; i < 32; ++i) {
            const float* wp =
                w22o + ((size_t)b * CI + grp * 32 + i) * CI + jb * 8;
#pragma unroll
            for (int j = 0; j < 8; ++j) acc[i] = fmaf(wp[j], yv[j], acc[i]);
        }
    }

#pragma unroll
    for (int i = 0; i < 32; ++i) {
        const int   cc    = grp * 32 + i;
        const float scale = g2[cc] / sqrtf(v2[cc] + EPSN);
        const float shift = be2[cc] - m2[cc] * scale;
        out2[((size_t)b * CI + cc) * PP + p0 + px] =
            fmaxf(fmaf(acc[i], scale, shift), 0.0f);
    }
}

// ---------------------------------------------------------------------------
// K6: conv3 (3x3, 128->128, no bias) + BN3 + ReLU -> d_out
// ---------------------------------------------------------------------------
__global__ __launch_bounds__(256) void k_conv3(
    const float* __restrict__ xin, const float* __restrict__ w3,
    const float* __restrict__ g3, const float* __restrict__ be3,
    const float* __restrict__ m3, const float* __restrict__ v3,
    float* __restrict__ outp)
{
    const int t    = threadIdx.x;
    const int tile = blockIdx.x;   // 0..63
    const int gi   = blockIdx.y;   // 0..3
    const int b    = blockIdx.z;

    const int tx = (tile & 1) * 64;
    const int ty = (tile >> 1) * 4;
    const int x  = tx + (t & 63);
    const int y  = ty + (t >> 6);
    const int og = gi * 32;

    float acc[32];
#pragma unroll
    for (int o = 0; o < 32; ++o) acc[o] = 0.0f;

    for (int c = 0; c < CI; ++c) {
        const float* src = xin + ((size_t)b * CI + c) * PP;
        float r[9];
#pragma unroll
        for (int dy = 0; dy < 3; ++dy) {
            const int  ry  = y + dy - 1;
            const bool oky = ((unsigned)ry < (unsigned)HH);
#pragma unroll
            for (int dx = 0; dx < 3; ++dx) {
                const int  rx = x + dx - 1;
                const bool ok = oky && ((unsigned)rx < (unsigned)WW);
                r[dy * 3 + dx] = ok ? src[ry * WW + rx] : 0.0f;
            }
        }
#pragma unroll
        for (int o = 0; o < 32; ++o) {
            const float* wp = w3 + (((size_t)(og + o)) * CI + c) * 9;
#pragma unroll
            for (int k = 0; k < 9; ++k) acc[o] = fmaf(wp[k], r[k], acc[o]);
        }
    }

    const size_t pbase = (size_t)y * WW + x;
#pragma unroll
    for (int o = 0; o < 32; ++o) {
        const int   cc    = og + o;
        const float scale = g3[cc] / sqrtf(v3[cc] + EPSN);
        const float shift = be3[cc] - m3[cc] * scale;
        outp[((size_t)b * CI + cc) * PP + pbase] =
            fmaxf(fmaf(acc[o], scale, shift), 0.0f);
    }
}

// ---------------------------------------------------------------------------
extern "C" void kernel_launch(void* const* d_in, const int* in_sizes, int n_in,
                              void* d_out, int out_size, void* d_ws, size_t ws_size,
                              hipStream_t stream)
{
    (void)in_sizes; (void)n_in; (void)out_size; (void)ws_size;

    const float* input  = (const float*)d_in[0];
    const float* weight = (const float*)d_in[1];
    const float* w11    = (const float*)d_in[2];
    const float* b11    = (const float*)d_in[3];
    const float* w12    = (const float*)d_in[4];
    const float* b12    = (const float*)d_in[5];
    const float* w21    = (const float*)d_in[6];
    const float* b21    = (const float*)d_in[7];
    const float* w22    = (const float*)d_in[8];
    const float* b22    = (const float*)d_in[9];
    const float* g1     = (const float*)d_in[10];
    const float* be1    = (const float*)d_in[11];
    const float* m1     = (const float*)d_in[12];
    const float* v1     = (const float*)d_in[13];
    const float* g2     = (const float*)d_in[14];
    const float* be2    = (const float*)d_in[15];
    const float* m2     = (const float*)d_in[16];
    const float* v2     = (const float*)d_in[17];
    const float* w3     = (const float*)d_in[18];
    const float* g3     = (const float*)d_in[19];
    const float* be3    = (const float*)d_in[20];
    const float* m3     = (const float*)d_in[21];
    const float* v3     = (const float*)d_in[22];

    // Workspace layout (floats): y1 | y2(->bmm out) | local | pooled | w22o
    float* ws     = (float*)d_ws;
    float* y1     = ws;                    // 8388608 floats
    float* y2o    = ws + 8388608;          // 8388608 (y2, later bmm output)
    float* loc    = ws + 16777216;         // 8388608
    float* pooled = ws + 25165824;         // 512
    float* w22o   = ws + 25166336;         // 65536
    float* outp   = (float*)d_out;

    k_conv_dual<<<dim3(64, 8, BB), 256, 0, stream>>>(
        input, weight, w11, b11, w21, b21, y1, y2o);
    k_pool<<<dim3(CI, BB), 256, 0, stream>>>(y2o, pooled);
    k_w22<<<dim3(64, BB), 256, 0, stream>>>(w22, b22, pooled, w22o);   // 64*256 = 16384 outputs
    k_guided<<<dim3(PP / 64, BB), 256, 0, stream>>>(
        input, y1, w12, b12, g1, be1, m1, v1, loc);
    k_bmm<<<dim3(PP / 64, BB), 256, 0, stream>>>(
        loc, w22o, g2, be2, m2, v2, y2o);
    k_conv3<<<dim3(64, 4, BB), 256, 0, stream>>>(
        y2o, w3, g3, be3, m3, v3, outp);
}

// Round 3
// 934.355 us; speedup vs baseline: 2.2820x; 2.2820x over previous
//
#include <hip/hip_runtime.h>
#include <math.h>

// Problem constants (B=4, Ci=128, Cg=64, H=W=128), all fp32.
#define BB   4
#define CI   128
#define CG   64
#define CIN  192
#define HH   128
#define WW   128
#define PP   16384
#define EPSN 1e-5f

typedef unsigned short u16;
typedef unsigned int   u32;
typedef __attribute__((ext_vector_type(8))) short bf16x8;
typedef __attribute__((ext_vector_type(4))) float f32x4;

__device__ __forceinline__ u16 f2bf(float x) {
    union { float f; u32 u; } a; a.f = x;
    u32 u = a.u;
    return (u16)((u + 0x7FFFu + ((u >> 16) & 1u)) >> 16);   // RNE
}
__device__ __forceinline__ float bf2f(u16 h) {
    union { u32 u; float f; } a; a.u = ((u32)h) << 16; return a.f;
}

// ---------------------------------------------------------------------------
// P1/P3: pad(1) + NCHW->NHWC transpose + bf16 hi/lo split.
// dst[b][rr][cc][ch], rr,cc in [0,130), border rows/cols zeroed.
// ---------------------------------------------------------------------------
__global__ __launch_bounds__(256) void k_pack(
    const float* __restrict__ src0, int nch0,
    const float* __restrict__ src1, int nch1,
    u16* __restrict__ dhi, u16* __restrict__ dlo, int cinp)
{
    const int rr = blockIdx.x;   // 0..129
    const int b  = blockIdx.y;
    const int t  = threadIdx.x;
    u16* rh = dhi + ((size_t)b * 130 + rr) * 130 * cinp;
    u16* rl = dlo + ((size_t)b * 130 + rr) * 130 * cinp;

    if (rr == 0 || rr == 129) {
        u32* rh4 = (u32*)rh; u32* rl4 = (u32*)rl;
        const int tot = 130 * cinp / 2;      // u32 count
        for (int i = t; i < tot; i += 256) { rh4[i] = 0u; rl4[i] = 0u; }
        return;
    }
    const int y = rr - 1;
    for (int i = t; i < cinp; i += 256) {     // cc = 0 and 129 borders
        rh[i] = 0; rl[i] = 0;
        rh[129 * cinp + i] = 0; rl[129 * cinp + i] = 0;
    }

    __shared__ float xs[32][129];
    for (int ck = 0; ck < cinp / 32; ++ck) {
        __syncthreads();
        for (int i = t; i < 32 * 128; i += 256) {
            const int ch = i >> 7, col = i & 127;
            const int c = ck * 32 + ch;
            const float* sp = (c < nch0)
                ? src0 + ((size_t)b * nch0 + c) * PP
                : src1 + ((size_t)b * nch1 + (c - nch0)) * PP;
            xs[ch][col] = sp[y * WW + col];
        }
        __syncthreads();
        for (int i = t; i < 512; i += 256) {
            const int col = i >> 2, oct = i & 3;
            u16 hh[8], ll[8];
#pragma unroll
            for (int j = 0; j < 8; ++j) {
                const float v = xs[oct * 8 + j][col];
                const u16 h = f2bf(v);
                hh[j] = h; ll[j] = f2bf(v - bf2f(h));
            }
            const size_t off = (size_t)(col + 1) * cinp + ck * 32 + oct * 8;
            uint4 vh, vl;
            vh.x = (u32)hh[0] | ((u32)hh[1] << 16); vh.y = (u32)hh[2] | ((u32)hh[3] << 16);
            vh.z = (u32)hh[4] | ((u32)hh[5] << 16); vh.w = (u32)hh[6] | ((u32)hh[7] << 16);
            vl.x = (u32)ll[0] | ((u32)ll[1] << 16); vl.y = (u32)ll[2] | ((u32)ll[3] << 16);
            vl.z = (u32)ll[4] | ((u32)ll[5] << 16); vl.w = (u32)ll[6] | ((u32)ll[7] << 16);
            *(uint4*)(rh + off) = vh;
            *(uint4*)(rl + off) = vl;
        }
    }
}

// ---------------------------------------------------------------------------
// P2: weight rearrange + split. dst[half][mb][ck][tap][oc(128)][kk(32)] bf16.
// src w[oc][cin][3][3] (OIHW fp32).
// ---------------------------------------------------------------------------
__global__ __launch_bounds__(256) void k_wpack(
    const float* __restrict__ w0, const float* __restrict__ w1,
    u16* __restrict__ dst, int nmb, int nck, int cin)
{
    const int total = nmb * nck * 9 * 128 * 4;
    const int idx = blockIdx.x * 256 + threadIdx.x;
    if (idx >= total) return;
    const int oct = idx & 3; int r2 = idx >> 2;
    const int oc = r2 & 127; r2 >>= 7;
    const int tap = r2 % 9; r2 /= 9;
    const int ck = r2 % nck; r2 /= nck;
    const int mb = r2;
    const float* w = mb ? w1 : w0;
    u16 hh[8], ll[8];
#pragma unroll
    for (int j = 0; j < 8; ++j) {
        const int c = ck * 32 + oct * 8 + j;
        const float v = w[((size_t)oc * cin + c) * 9 + tap];
        const u16 h = f2bf(v);
        hh[j] = h; ll[j] = f2bf(v - bf2f(h));
    }
    const size_t halfs = (size_t)nmb * nck * 9 * 128 * 32;
    const size_t base = ((((size_t)mb * nck + ck) * 9 + tap) * 128 + oc) * 32 + oct * 8;
    uint4 vh, vl;
    vh.x = (u32)hh[0] | ((u32)hh[1] << 16); vh.y = (u32)hh[2] | ((u32)hh[3] << 16);
    vh.z = (u32)hh[4] | ((u32)hh[5] << 16); vh.w = (u32)hh[6] | ((u32)hh[7] << 16);
    vl.x = (u32)ll[0] | ((u32)ll[1] << 16); vl.y = (u32)ll[2] | ((u32)ll[3] << 16);
    vl.z = (u32)ll[4] | ((u32)ll[5] << 16); vl.w = (u32)ll[6] | ((u32)ll[7] << 16);
    *(uint4*)(dst + base) = vh;
    *(uint4*)(dst + halfs + base) = vl;
}

// ---------------------------------------------------------------------------
// Main 3x3 conv as implicit-GEMM MFMA, split-bf16 3-pass.
// Block: 128 out-ch x 128 px (one image row). 4 waves (2x2 of 64x64).
// K-loop: NCK channel-chunks x 9 taps; X staged once per chunk (halo in LDS),
// A (weights) staged per tap. All staging via global_load_lds width=16.
// ---------------------------------------------------------------------------
template<int NCK, bool DUAL>
__global__ __launch_bounds__(256, 2) void k_conv_mfma(
    const u16* __restrict__ xhi, const u16* __restrict__ xlo,
    const u16* __restrict__ wA,
    const float* __restrict__ bias0, const float* __restrict__ bias1,
    const float* __restrict__ bng, const float* __restrict__ bnb,
    const float* __restrict__ bnm, const float* __restrict__ bnv,
    float* __restrict__ dst0, float* __restrict__ dst1)
{
    constexpr int CINP  = NCK * 32;
    constexpr int MBT   = DUAL ? 2 : 1;
    constexpr size_t WHALF = (size_t)MBT * NCK * 9 * 128 * 32;

    __shared__ u16 Xs[2][3][144][32];   // [half][r][cc][ch]  55296 B
    __shared__ u16 As[2][128][32];      // [half][oc][kk]     16384 B

    const int t    = threadIdx.x;
    const int wave = t >> 6;
    const int lane = t & 63;
    const int wm   = wave >> 1, wn = wave & 1;
    const int y    = blockIdx.x;
    const int mb   = blockIdx.y;
    const int b    = blockIdx.z;
    const int l15  = lane & 15;
    const int kg   = lane >> 4;

    f32x4 acc[4][4];
    if (DUAL) {
        const float* bp = mb ? bias1 : bias0;
#pragma unroll
        for (int fm = 0; fm < 4; ++fm) {
            const int ocb = wm * 64 + fm * 16 + kg * 4;
#pragma unroll
            for (int j = 0; j < 4; ++j) {
                const float bv = bp[ocb + j];
#pragma unroll
                for (int fn = 0; fn < 4; ++fn) acc[fm][fn][j] = bv;
            }
        }
    } else {
#pragma unroll
        for (int fm = 0; fm < 4; ++fm)
#pragma unroll
            for (int fn = 0; fn < 4; ++fn)
#pragma unroll
                for (int j = 0; j < 4; ++j) acc[fm][fn][j] = 0.0f;
    }

    const size_t xrow = (size_t)130 * CINP;   // ushorts per padded row

    for (int ck = 0; ck < NCK; ++ck) {
        __syncthreads();   // previous chunk's LDS reads complete
        // ---- stage X chunk: 2 halves x 3 rows x 9 issues of 1024B ----
        for (int idx = wave; idx < 54; idx += 4) {
            const int h = idx / 27, rem = idx % 27;
            const int r = rem / 9, iss = rem % 9;
            const u16* gb = (h ? xlo : xhi)
                + ((size_t)b * 130 + (y + r)) * xrow + ck * 32;
            const int o  = iss * 1024 + lane * 16;   // byte in LDS region
            const int cc = o >> 6, rb = o & 63;
            const char* gaddr = (const char*)gb + (size_t)cc * (CINP * 2) + rb;
            char* laddr = ((char*)&Xs[h][r][0][0]) + iss * 1024;
            __builtin_amdgcn_global_load_lds(
                (const __attribute__((address_space(1))) void*)gaddr,
                (__attribute__((address_space(3))) void*)laddr, 16, 0, 0);
        }
        for (int tap = 0; tap < 9; ++tap) {
            // ---- stage A tile for this tap: 2 halves x 8 issues ----
            for (int idx = wave; idx < 16; idx += 4) {
                const int h = idx >> 3, iss = idx & 7;
                const u16* gb = wA + (size_t)h * WHALF
                    + ((((size_t)mb * NCK + ck) * 9 + tap) * 128 * 32);
                const char* gaddr = (const char*)gb + iss * 1024 + lane * 16;
                char* laddr = ((char*)&As[h][0][0]) + iss * 1024;
                __builtin_amdgcn_global_load_lds(
                    (const __attribute__((address_space(1))) void*)gaddr,
                    (__attribute__((address_space(3))) void*)laddr, 16, 0, 0);
            }
            asm volatile("s_waitcnt vmcnt(0)" ::: "memory");
            __syncthreads();

            const int dy = tap / 3, dx = tap % 3;
            bf16x8 ah[4], al[4], bh[4], bl[4];
#pragma unroll
            for (int f = 0; f < 4; ++f) {
                const int row = wm * 64 + f * 16 + l15;
                ah[f] = *(const bf16x8*)&As[0][row][kg * 8];
                al[f] = *(const bf16x8*)&As[1][row][kg * 8];
                const int cc = wn * 64 + f * 16 + l15 + dx;
                bh[f] = *(const bf16x8*)&Xs[0][dy][cc][kg * 8];
                bl[f] = *(const bf16x8*)&Xs[1][dy][cc][kg * 8];
            }
#pragma unroll
            for (int fm = 0; fm < 4; ++fm)
#pragma unroll
                for (int fn = 0; fn < 4; ++fn) {
                    acc[fm][fn] = __builtin_amdgcn_mfma_f32_16x16x32_bf16(
                        al[fm], bh[fn], acc[fm][fn], 0, 0, 0);
                    acc[fm][fn] = __builtin_amdgcn_mfma_f32_16x16x32_bf16(
                        ah[fm], bl[fn], acc[fm][fn], 0, 0, 0);
                    acc[fm][fn] = __builtin_amdgcn_mfma_f32_16x16x32_bf16(
                        ah[fm], bh[fn], acc[fm][fn], 0, 0, 0);
                }
            __syncthreads();   // protect As/Xs before next staging
        }
    }

    // ---- epilogue ----
    float* dst = (DUAL && mb) ? dst1 : dst0;
#pragma unroll
    for (int fm = 0; fm < 4; ++fm) {
#pragma unroll
        for (int j = 0; j < 4; ++j) {
            const int oc = wm * 64 + fm * 16 + kg * 4 + j;
            float sc = 1.0f, sh = 0.0f;
            if (!DUAL) {
                sc = bng[oc] * rsqrtf(bnv[oc] + EPSN);
                sh = bnb[oc] - bnm[oc] * sc;
            }
            const size_t obase = ((size_t)b * CI + oc) * PP + (size_t)y * WW;
#pragma unroll
            for (int fn = 0; fn < 4; ++fn) {
                const int px = wn * 64 + fn * 16 + l15;
                float v = acc[fm][fn][j];
                if (!DUAL) v = fmaf(v, sc, sh);
                dst[obase + px] = fmaxf(v, 0.0f);
            }
        }
    }
}

// ---------------------------------------------------------------------------
// K2: global average pool of y2 -> pooled[b][c]
// ---------------------------------------------------------------------------
__global__ __launch_bounds__(256) void k_pool(
    const float* __restrict__ y2, float* __restrict__ pooled)
{
    const int c = blockIdx.x, b = blockIdx.y, t = threadIdx.x;
    const float* src = y2 + ((size_t)b * CI + c) * PP;
    float s = 0.0f;
    for (int i = t; i < PP; i += 256) s += src[i];
    __shared__ float red[256];
    red[t] = s;
    __syncthreads();
    for (int st = 128; st > 0; st >>= 1) {
        if (t < st) red[t] += red[t + st];
        __syncthreads();
    }
    if (t == 0) pooled[b * CI + c] = red[0] * (1.0f / PP);
}

// ---------------------------------------------------------------------------
// K3: w22o[b][o] = dot(w22[o,:], pooled[b,:]) + b22[o]
// ---------------------------------------------------------------------------
__global__ __launch_bounds__(256) void k_w22(
    const float* __restrict__ w22, const float* __restrict__ b22,
    const float* __restrict__ pooled, float* __restrict__ w22o)
{
    const int b = blockIdx.y;
    const int o = blockIdx.x * 256 + threadIdx.x;
    __shared__ float pl[CI];
    if (threadIdx.x < CI) pl[threadIdx.x] = pooled[b * CI + threadIdx.x];
    __syncthreads();
    const float4* wr = (const float4*)(w22 + (size_t)o * CI);
    float acc = b22[o];
#pragma unroll 8
    for (int c4 = 0; c4 < CI / 4; ++c4) {
        const float4 w = wr[c4];
        acc += w.x * pl[c4 * 4 + 0] + w.y * pl[c4 * 4 + 1] +
               w.z * pl[c4 * 4 + 2] + w.w * pl[c4 * 4 + 3];
    }
    w22o[(size_t)b * CI * CI + o] = acc;
}

// ---------------------------------------------------------------------------
// K4: fused conv12 (1x1, 128->1152) + guided depthwise 3x3 + BN1 + ReLU.
// ---------------------------------------------------------------------------
__global__ __launch_bounds__(256) void k_guided(
    const float* __restrict__ input, const float* __restrict__ y1,
    const float* __restrict__ w12, const float* __restrict__ b12,
    const float* __restrict__ g1, const float* __restrict__ be1,
    const float* __restrict__ m1, const float* __restrict__ v1,
    float* __restrict__ localb)
{
    __shared__ float ly[CI][64];
    const int b  = blockIdx.y;
    const int p0 = blockIdx.x * 64;
    const int t  = threadIdx.x;

    for (int i = t; i < CI * 64; i += 256) {
        const int ch = i >> 6, pp = i & 63;
        ly[ch][pp] = y1[((size_t)b * CI + ch) * PP + p0 + pp];
    }
    __syncthreads();

    const int px  = t & 63;
    const int grp = __builtin_amdgcn_readfirstlane(t >> 6);
    const int p   = p0 + px;
    const int y   = p >> 7;
    const int x   = p & 127;

    for (int ci = 0; ci < 32; ++ci) {
        const int cc = grp * 32 + ci;
        float acc9[9];
        const float* bp = b12 + cc * 9;
#pragma unroll
        for (int k = 0; k < 9; ++k) acc9[k] = bp[k];

        for (int cb = 0; cb < CI / 8; ++cb) {
            float yv[8];
#pragma unroll
            for (int j = 0; j < 8; ++j) yv[j] = ly[cb * 8 + j][px];
#pragma unroll
            for (int k = 0; k < 9; ++k) {
                const float* wp = w12 + ((size_t)(cc * 9 + k)) * CI + cb * 8;
#pragma unroll
                for (int j = 0; j < 8; ++j) acc9[k] = fmaf(wp[j], yv[j], acc9[k]);
            }
        }

        const float* src = input + ((size_t)b * CI + cc) * PP;
        float lsum = 0.0f;
#pragma unroll
        for (int dy = 0; dy < 3; ++dy) {
            const int  ry  = y + dy - 1;
            const bool oky = ((unsigned)ry < (unsigned)HH);
#pragma unroll
            for (int dx = 0; dx < 3; ++dx) {
                const int  rx = x + dx - 1;
                const bool ok = oky && ((unsigned)rx < (unsigned)WW);
                const float pv = ok ? src[ry * WW + rx] : 0.0f;
                lsum = fmaf(acc9[dy * 3 + dx], pv, lsum);
            }
        }

        const float scale = g1[cc] / sqrtf(v1[cc] + EPSN);
        const float shift = be1[cc] - m1[cc] * scale;
        localb[((size_t)b * CI + cc) * PP + p] =
            fmaxf(fmaf(lsum, scale, shift), 0.0f);
    }
}

// ---------------------------------------------------------------------------
// K5: channel-mix bmm + BN2 + ReLU
// ---------------------------------------------------------------------------
__global__ __launch_bounds__(256) void k_bmm(
    const float* __restrict__ localb, const float* __restrict__ w22o,
    const float* __restrict__ g2, const float* __restrict__ be2,
    const float* __restrict__ m2, const float* __restrict__ v2,
    float* __restrict__ out2)
{
    __shared__ float ll[CI][64];
    const int b  = blockIdx.y;
    const int p0 = blockIdx.x * 64;
    const int t  = threadIdx.x;

    for (int i = t; i < CI * 64; i += 256) {
        const int ch = i >> 6, pp = i & 63;
        ll[ch][pp] = localb[((size_t)b * CI + ch) * PP + p0 + pp];
    }
    __syncthreads();

    const int px  = t & 63;
    const int grp = __builtin_amdgcn_readfirstlane(t >> 6);

    float acc[32];
#pragma unroll
    for (int i = 0; i < 32; ++i) acc[i] = 0.0f;

    for (int jb = 0; jb < CI / 8; ++jb) {
        float yv[8];
#pragma unroll
        for (int j = 0; j < 8; ++j) yv[j] = ll[jb * 8 + j][px];
#pragma unroll
        for (int i = 0; i < 32; ++i) {
            const float* wp =
                w22o + ((size_t)b * CI + grp * 32 + i) * CI + jb * 8;
#pragma unroll
            for (int j = 0; j < 8; ++j) acc[i] = fmaf(wp[j], yv[j], acc[i]);
        }
    }

#pragma unroll
    for (int i = 0; i < 32; ++i) {
        const int   cc    = grp * 32 + i;
        const float scale = g2[cc] / sqrtf(v2[cc] + EPSN);
        const float shift = be2[cc] - m2[cc] * scale;
        out2[((size_t)b * CI + cc) * PP + p0 + px] =
            fmaxf(fmaf(acc[i], scale, shift), 0.0f);
    }
}

// ---------------------------------------------------------------------------
extern "C" void kernel_launch(void* const* d_in, const int* in_sizes, int n_in,
                              void* d_out, int out_size, void* d_ws, size_t ws_size,
                              hipStream_t stream)
{
    (void)in_sizes; (void)n_in; (void)out_size; (void)ws_size;

    const float* input  = (const float*)d_in[0];
    const float* weight = (const float*)d_in[1];
    const float* w11    = (const float*)d_in[2];
    const float* b11    = (const float*)d_in[3];
    const float* w12    = (const float*)d_in[4];
    const float* b12    = (const float*)d_in[5];
    const float* w21    = (const float*)d_in[6];
    const float* b21    = (const float*)d_in[7];
    const float* w22    = (const float*)d_in[8];
    const float* b22    = (const float*)d_in[9];
    const float* g1     = (const float*)d_in[10];
    const float* be1    = (const float*)d_in[11];
    const float* m1     = (const float*)d_in[12];
    const float* v1     = (const float*)d_in[13];
    const float* g2     = (const float*)d_in[14];
    const float* be2    = (const float*)d_in[15];
    const float* m2     = (const float*)d_in[16];
    const float* v2     = (const float*)d_in[17];
    const float* w3     = (const float*)d_in[18];
    const float* g3     = (const float*)d_in[19];
    const float* be3    = (const float*)d_in[20];
    const float* m3     = (const float*)d_in[21];
    const float* v3     = (const float*)d_in[22];

    // Workspace (float units):
    // y1(8388608) | y2o(8388608) | pooled(512) | w22o(65536) |
    // wAd(442368) | wA3(147456) | shared region: loc (8388608) / xpad (12981248)
    float* ws     = (float*)d_ws;
    float* y1     = ws;
    float* y2o    = ws + 8388608;
    float* pooled = ws + 16777216;
    float* w22o   = ws + 16777728;
    u16*   wAd    = (u16*)(ws + 16843264);     // 884736 u16
    u16*   wA3    = (u16*)(ws + 17285632);     // 294912 u16
    float* loc    = ws + 17433088;             // aliases xpad region (disjoint lifetimes)
    u16*   xhi    = (u16*)(ws + 17433088);
    u16*   xlo    = xhi + 12979200;            // per-half 4*130*130*192, +4096 u16 slack after
    u16*   xhi3   = xhi;
    u16*   xlo3   = xhi + 8652800;             // per-half 4*130*130*128
    float* outp   = (float*)d_out;

    // conv11+conv21 via MFMA
    k_pack<<<dim3(130, BB), 256, 0, stream>>>(input, CI, weight, CG, xhi, xlo, CIN);
    k_wpack<<<dim3((55296 + 255) / 256), 256, 0, stream>>>(w11, w21, wAd, 2, 6, CIN);
    k_wpack<<<dim3((18432 + 255) / 256), 256, 0, stream>>>(w3, w3, wA3, 1, 4, CI);
    k_conv_mfma<6, true><<<dim3(128, 2, BB), 256, 0, stream>>>(
        xhi, xlo, wAd, b11, b21, nullptr, nullptr, nullptr, nullptr, y1, y2o);

    k_pool<<<dim3(CI, BB), 256, 0, stream>>>(y2o, pooled);
    k_w22<<<dim3(64, BB), 256, 0, stream>>>(w22, b22, pooled, w22o);
    k_guided<<<dim3(PP / 64, BB), 256, 0, stream>>>(
        input, y1, w12, b12, g1, be1, m1, v1, loc);
    k_bmm<<<dim3(PP / 64, BB), 256, 0, stream>>>(
        loc, w22o, g2, be2, m2, v2, y2o);

    // conv3 via MFMA (re-pack bmm output; loc is dead by now)
    k_pack<<<dim3(130, BB), 256, 0, stream>>>(y2o, CI, nullptr, 0, xhi3, xlo3, CI);
    k_conv_mfma<4, false><<<dim3(128, 1, BB), 256, 0, stream>>>(
        xhi3, xlo3, wA3, nullptr, nullptr, g3, be3, m3, v3, outp, nullptr);
}

// Round 4
// 577.161 us; speedup vs baseline: 3.6943x; 1.6189x over previous
//
#include <hip/hip_runtime.h>
#include <math.h>

// Problem constants (B=4, Ci=128, Cg=64, H=W=128), all fp32.
#define BB   4
#define CI   128
#define CG   64
#define CIN  192
#define HH   128
#define WW   128
#define PP   16384
#define EPSN 1e-5f

typedef unsigned short u16;
typedef unsigned int   u32;
typedef __attribute__((ext_vector_type(8))) short bf16x8;
typedef __attribute__((ext_vector_type(4))) float f32x4;

__device__ __forceinline__ u16 f2bf(float x) {
    union { float f; u32 u; } a; a.f = x;
    u32 u = a.u;
    return (u16)((u + 0x7FFFu + ((u >> 16) & 1u)) >> 16);   // RNE
}
__device__ __forceinline__ float bf2f(u16 h) {
    union { u32 u; float f; } a; a.u = ((u32)h) << 16; return a.f;
}
// XOR-swizzle for [px][c] bf16 row-images (256B per px row): spreads the
// 16 l15-lanes of a ds_read_b128 across 8 16B slots (bank-conflict-free).
__device__ __forceinline__ u32 swz(u32 o) { return o ^ ((o >> 4) & 0x70u); }

__device__ __forceinline__ void gld_lds16(const void* g, void* l) {
    __builtin_amdgcn_global_load_lds(
        (const __attribute__((address_space(1))) void*)g,
        (__attribute__((address_space(3))) void*)l, 16, 0, 0);
}

// ---------------------------------------------------------------------------
// P1: pad(1) + NCHW->NHWC transpose + bf16 hi/lo split (input||weight).
// ---------------------------------------------------------------------------
__global__ __launch_bounds__(256) void k_pack(
    const float* __restrict__ src0, int nch0,
    const float* __restrict__ src1, int nch1,
    u16* __restrict__ dhi, u16* __restrict__ dlo, int cinp)
{
    const int rr = blockIdx.x;   // 0..129
    const int b  = blockIdx.y;
    const int t  = threadIdx.x;
    u16* rh = dhi + ((size_t)b * 130 + rr) * 130 * cinp;
    u16* rl = dlo + ((size_t)b * 130 + rr) * 130 * cinp;

    if (rr == 0 || rr == 129) {
        u32* rh4 = (u32*)rh; u32* rl4 = (u32*)rl;
        const int tot = 130 * cinp / 2;
        for (int i = t; i < tot; i += 256) { rh4[i] = 0u; rl4[i] = 0u; }
        return;
    }
    const int y = rr - 1;
    for (int i = t; i < cinp; i += 256) {
        rh[i] = 0; rl[i] = 0;
        rh[129 * cinp + i] = 0; rl[129 * cinp + i] = 0;
    }

    __shared__ float xs[32][129];
    for (int ck = 0; ck < cinp / 32; ++ck) {
        __syncthreads();
        for (int i = t; i < 32 * 128; i += 256) {
            const int ch = i >> 7, col = i & 127;
            const int c = ck * 32 + ch;
            const float* sp = (c < nch0)
                ? src0 + ((size_t)b * nch0 + c) * PP
                : src1 + ((size_t)b * nch1 + (c - nch0)) * PP;
            xs[ch][col] = sp[y * WW + col];
        }
        __syncthreads();
        for (int i = t; i < 512; i += 256) {
            const int col = i >> 2, oct = i & 3;
            u16 hh[8], ll[8];
#pragma unroll
            for (int j = 0; j < 8; ++j) {
                const float v = xs[oct * 8 + j][col];
                const u16 h = f2bf(v);
                hh[j] = h; ll[j] = f2bf(v - bf2f(h));
            }
            const size_t off = (size_t)(col + 1) * cinp + ck * 32 + oct * 8;
            uint4 vh, vl;
            vh.x = (u32)hh[0] | ((u32)hh[1] << 16); vh.y = (u32)hh[2] | ((u32)hh[3] << 16);
            vh.z = (u32)hh[4] | ((u32)hh[5] << 16); vh.w = (u32)hh[6] | ((u32)hh[7] << 16);
            vl.x = (u32)ll[0] | ((u32)ll[1] << 16); vl.y = (u32)ll[2] | ((u32)ll[3] << 16);
            vl.z = (u32)ll[4] | ((u32)ll[5] << 16); vl.w = (u32)ll[6] | ((u32)ll[7] << 16);
            *(uint4*)(rh + off) = vh;
            *(uint4*)(rl + off) = vl;
        }
    }
}

// ---------------------------------------------------------------------------
// P2: 3x3 weight rearrange + split. dst[half][mb][ck][tap][oc(128)][kk(32)].
// ---------------------------------------------------------------------------
__global__ __launch_bounds__(256) void k_wpack(
    const float* __restrict__ w0, const float* __restrict__ w1,
    u16* __restrict__ dst, int nmb, int nck, int cin)
{
    const int total = nmb * nck * 9 * 128 * 4;
    const int idx = blockIdx.x * 256 + threadIdx.x;
    if (idx >= total) return;
    const int oct = idx & 3; int r2 = idx >> 2;
    const int oc = r2 & 127; r2 >>= 7;
    const int tap = r2 % 9; r2 /= 9;
    const int ck = r2 % nck; r2 /= nck;
    const int mb = r2;
    const float* w = mb ? w1 : w0;
    u16 hh[8], ll[8];
#pragma unroll
    for (int j = 0; j < 8; ++j) {
        const int c = ck * 32 + oct * 8 + j;
        const float v = w[((size_t)oc * cin + c) * 9 + tap];
        const u16 h = f2bf(v);
        hh[j] = h; ll[j] = f2bf(v - bf2f(h));
    }
    const size_t halfs = (size_t)nmb * nck * 9 * 128 * 32;
    const size_t base = ((((size_t)mb * nck + ck) * 9 + tap) * 128 + oc) * 32 + oct * 8;
    uint4 vh, vl;
    vh.x = (u32)hh[0] | ((u32)hh[1] << 16); vh.y = (u32)hh[2] | ((u32)hh[3] << 16);
    vh.z = (u32)hh[4] | ((u32)hh[5] << 16); vh.w = (u32)hh[6] | ((u32)hh[7] << 16);
    vl.x = (u32)ll[0] | ((u32)ll[1] << 16); vl.y = (u32)ll[2] | ((u32)ll[3] << 16);
    vl.z = (u32)ll[4] | ((u32)ll[5] << 16); vl.w = (u32)ll[6] | ((u32)ll[7] << 16);
    *(uint4*)(dst + base) = vh;
    *(uint4*)(dst + halfs + base) = vl;
}

// ---------------------------------------------------------------------------
// P4: w12 (1x1, [1152][128] OIHW) -> w12p[half][tap][cc][c] split bf16.
// ---------------------------------------------------------------------------
__global__ __launch_bounds__(256) void k_wpack12(
    const float* __restrict__ w12, u16* __restrict__ dst)
{
    const int idx = blockIdx.x * 256 + threadIdx.x;   // 18432 = 1152*16
    if (idx >= 18432) return;
    const int oct = idx & 15;
    const int g   = idx >> 4;            // 0..1151 = cc*9+tap
    const int cc  = g / 9, tap = g % 9;
    u16 hh[8], ll[8];
#pragma unroll
    for (int j = 0; j < 8; ++j) {
        const float v = w12[(size_t)g * 128 + oct * 8 + j];
        const u16 h = f2bf(v);
        hh[j] = h; ll[j] = f2bf(v - bf2f(h));
    }
    const size_t base = ((size_t)(tap * 128 + cc)) * 128 + oct * 8;
    uint4 vh, vl;
    vh.x = (u32)hh[0] | ((u32)hh[1] << 16); vh.y = (u32)hh[2] | ((u32)hh[3] << 16);
    vh.z = (u32)hh[4] | ((u32)hh[5] << 16); vh.w = (u32)hh[6] | ((u32)hh[7] << 16);
    vl.x = (u32)ll[0] | ((u32)ll[1] << 16); vl.y = (u32)ll[2] | ((u32)ll[3] << 16);
    vl.z = (u32)ll[4] | ((u32)ll[5] << 16); vl.w = (u32)ll[6] | ((u32)ll[7] << 16);
    *(uint4*)(dst + base) = vh;
    *(uint4*)(dst + 147456 + base) = vl;
}

// ---------------------------------------------------------------------------
// Main 3x3 conv as implicit-GEMM MFMA, split-bf16 3-pass.
// DUAL mb=0 writes y1 as swizzled split [px][c] row-images (for k_guided_mfma).
// ---------------------------------------------------------------------------
template<int NCK, bool DUAL>
__global__ __launch_bounds__(256, 2) void k_conv_mfma(
    const u16* __restrict__ xhi, const u16* __restrict__ xlo,
    const u16* __restrict__ wA,
    const float* __restrict__ bias0, const float* __restrict__ bias1,
    const float* __restrict__ bng, const float* __restrict__ bnb,
    const float* __restrict__ bnm, const float* __restrict__ bnv,
    float* __restrict__ dst0, float* __restrict__ dst1,
    u16* __restrict__ y1ph, u16* __restrict__ y1pl)
{
    constexpr int CINP  = NCK * 32;
    constexpr int MBT   = DUAL ? 2 : 1;
    constexpr size_t WHALF = (size_t)MBT * NCK * 9 * 128 * 32;

    __shared__ char smem[73728];
    u16 (*Xs)[3][144][32] = (u16(*)[3][144][32])smem;          // 55296 B
    u16 (*As)[128][32]    = (u16(*)[128][32])(smem + 55296);   // 16384 B

    const int t    = threadIdx.x;
    const int wave = t >> 6;
    const int lane = t & 63;
    const int wm   = wave >> 1, wn = wave & 1;
    const int y    = blockIdx.x;
    const int mb   = blockIdx.y;
    const int b    = blockIdx.z;
    const int l15  = lane & 15;
    const int kg   = lane >> 4;

    f32x4 acc[4][4];
    if (DUAL) {
        const float* bp = mb ? bias1 : bias0;
#pragma unroll
        for (int fm = 0; fm < 4; ++fm) {
            const int ocb = wm * 64 + fm * 16 + kg * 4;
#pragma unroll
            for (int j = 0; j < 4; ++j) {
                const float bv = bp[ocb + j];
#pragma unroll
                for (int fn = 0; fn < 4; ++fn) acc[fm][fn][j] = bv;
            }
        }
    } else {
#pragma unroll
        for (int fm = 0; fm < 4; ++fm)
#pragma unroll
            for (int fn = 0; fn < 4; ++fn)
#pragma unroll
                for (int j = 0; j < 4; ++j) acc[fm][fn][j] = 0.0f;
    }

    const size_t xrow = (size_t)130 * CINP;

    for (int ck = 0; ck < NCK; ++ck) {
        __syncthreads();
        for (int idx = wave; idx < 54; idx += 4) {
            const int h = idx / 27, rem = idx % 27;
            const int r = rem / 9, iss = rem % 9;
            const u16* gb = (h ? xlo : xhi)
                + ((size_t)b * 130 + (y + r)) * xrow + ck * 32;
            const int o  = iss * 1024 + lane * 16;
            const int cc = o >> 6, rb = o & 63;
            gld_lds16((const char*)gb + (size_t)cc * (CINP * 2) + rb,
                      ((char*)&Xs[h][r][0][0]) + iss * 1024);
        }
        for (int tap = 0; tap < 9; ++tap) {
            for (int idx = wave; idx < 16; idx += 4) {
                const int h = idx >> 3, iss = idx & 7;
                const u16* gb = wA + (size_t)h * WHALF
                    + ((((size_t)mb * NCK + ck) * 9 + tap) * 128 * 32);
                gld_lds16((const char*)gb + iss * 1024 + lane * 16,
                          ((char*)&As[h][0][0]) + iss * 1024);
            }
            asm volatile("s_waitcnt vmcnt(0)" ::: "memory");
            __syncthreads();

            const int dy = tap / 3, dx = tap % 3;
            bf16x8 ah[4], al[4], bh[4], bl[4];
#pragma unroll
            for (int f = 0; f < 4; ++f) {
                const int row = wm * 64 + f * 16 + l15;
                ah[f] = *(const bf16x8*)&As[0][row][kg * 8];
                al[f] = *(const bf16x8*)&As[1][row][kg * 8];
                const int cc = wn * 64 + f * 16 + l15 + dx;
                bh[f] = *(const bf16x8*)&Xs[0][dy][cc][kg * 8];
                bl[f] = *(const bf16x8*)&Xs[1][dy][cc][kg * 8];
            }
#pragma unroll
            for (int fm = 0; fm < 4; ++fm)
#pragma unroll
                for (int fn = 0; fn < 4; ++fn) {
                    acc[fm][fn] = __builtin_amdgcn_mfma_f32_16x16x32_bf16(
                        al[fm], bh[fn], acc[fm][fn], 0, 0, 0);
                    acc[fm][fn] = __builtin_amdgcn_mfma_f32_16x16x32_bf16(
                        ah[fm], bl[fn], acc[fm][fn], 0, 0, 0);
                    acc[fm][fn] = __builtin_amdgcn_mfma_f32_16x16x32_bf16(
                        ah[fm], bh[fn], acc[fm][fn], 0, 0, 0);
                }
            __syncthreads();
        }
    }

    if (DUAL && mb == 0) {
        // y1: ReLU + split + swizzled [px][c] image, coalesced 64KB store
        u16* img = (u16*)smem;   // reuse (past final barrier)
#pragma unroll
        for (int fm = 0; fm < 4; ++fm)
#pragma unroll
            for (int fn = 0; fn < 4; ++fn) {
                const int px = wn * 64 + fn * 16 + l15;
                const int c0 = wm * 64 + fm * 16 + kg * 4;
                u16 hh[4], ll[4];
#pragma unroll
                for (int j = 0; j < 4; ++j) {
                    const float v = fmaxf(acc[fm][fn][j], 0.0f);
                    const u16 h = f2bf(v);
                    hh[j] = h; ll[j] = f2bf(v - bf2f(h));
                }
                const u32 off = swz((u32)(px * 256 + c0 * 2));
                uint2 vh, vl;
                vh.x = (u32)hh[0] | ((u32)hh[1] << 16); vh.y = (u32)hh[2] | ((u32)hh[3] << 16);
                vl.x = (u32)ll[0] | ((u32)ll[1] << 16); vl.y = (u32)ll[2] | ((u32)ll[3] << 16);
                *(uint2*)((char*)img + off)         = vh;
                *(uint2*)((char*)img + 32768 + off) = vl;
            }
        __syncthreads();
        for (int h = 0; h < 2; ++h) {
            uint4* gd = (uint4*)((h ? y1pl : y1ph) + ((size_t)b * 128 + y) * 16384);
            const uint4* s4 = (const uint4*)(smem + h * 32768);
            for (int i = t; i < 2048; i += 256) gd[i] = s4[i];
        }
        return;
    }

    // fp32 output path (DUAL mb=1 -> y2o; !DUAL -> BN+ReLU -> out)
    float* dst = DUAL ? dst1 : dst0;
#pragma unroll
    for (int fm = 0; fm < 4; ++fm) {
#pragma unroll
        for (int j = 0; j < 4; ++j) {
            const int oc = wm * 64 + fm * 16 + kg * 4 + j;
            float sc = 1.0f, sh = 0.0f;
            if (!DUAL) {
                sc = bng[oc] * rsqrtf(bnv[oc] + EPSN);
                sh = bnb[oc] - bnm[oc] * sc;
            }
            const size_t obase = ((size_t)b * CI + oc) * PP + (size_t)y * WW;
#pragma unroll
            for (int fn = 0; fn < 4; ++fn) {
                const int px = wn * 64 + fn * 16 + l15;
                float v = acc[fm][fn][j];
                if (!DUAL) v = fmaf(v, sc, sh);
                dst[obase + px] = fmaxf(v, 0.0f);
            }
        }
    }
}

// ---------------------------------------------------------------------------
// K2: global average pool of y2 -> pooled[b][c]
// ---------------------------------------------------------------------------
__global__ __launch_bounds__(256) void k_pool(
    const float* __restrict__ y2, float* __restrict__ pooled)
{
    const int c = blockIdx.x, b = blockIdx.y, t = threadIdx.x;
    const float* src = y2 + ((size_t)b * CI + c) * PP;
    float s = 0.0f;
    for (int i = t; i < PP; i += 256) s += src[i];
    __shared__ float red[256];
    red[t] = s;
    __syncthreads();
    for (int st = 128; st > 0; st >>= 1) {
        if (t < st) red[t] += red[t + st];
        __syncthreads();
    }
    if (t == 0) pooled[b * CI + c] = red[0] * (1.0f / PP);
}

// ---------------------------------------------------------------------------
// K3: w22o = w22 . pooled + b22, emitted directly as split bf16 [half][b][i][j]
// ---------------------------------------------------------------------------
__global__ __launch_bounds__(256) void k_w22(
    const float* __restrict__ w22, const float* __restrict__ b22,
    const float* __restrict__ pooled, u16* __restrict__ w22p)
{
    const int b = blockIdx.y;
    const int o = blockIdx.x * 256 + threadIdx.x;
    __shared__ float pl[CI];
    if (threadIdx.x < CI) pl[threadIdx.x] = pooled[b * CI + threadIdx.x];
    __syncthreads();
    const float4* wr = (const float4*)(w22 + (size_t)o * CI);
    float acc = b22[o];
#pragma unroll 8
    for (int c4 = 0; c4 < CI / 4; ++c4) {
        const float4 w = wr[c4];
        acc += w.x * pl[c4 * 4 + 0] + w.y * pl[c4 * 4 + 1] +
               w.z * pl[c4 * 4 + 2] + w.w * pl[c4 * 4 + 3];
    }
    const u16 h = f2bf(acc);
    w22p[(size_t)b * 16384 + o] = h;
    w22p[65536 + (size_t)b * 16384 + o] = f2bf(acc - bf2f(h));
}

// ---------------------------------------------------------------------------
// K4: guided conv via MFMA: per tap G_k = W_k . y1 (split-bf16 3-pass),
// fold accL += G_k * x_shifted (fp32), BN1+ReLU, emit locp image.
// ---------------------------------------------------------------------------
__global__ __launch_bounds__(256, 2) void k_guided_mfma(
    const float* __restrict__ input,
    const u16* __restrict__ y1p,     // [half +8388608][b][y][16384 swz image]
    const u16* __restrict__ w12p,    // [half +147456][tap][cc][c]
    const float* __restrict__ b12,
    const float* __restrict__ g1, const float* __restrict__ be1,
    const float* __restrict__ m1, const float* __restrict__ v1,
    u16* __restrict__ locp)          // same image format as y1p
{
    __shared__ char smem[65536];
    const int t = threadIdx.x;
    const int wave = t >> 6, lane = t & 63;
    const int wm = wave >> 1, wn = wave & 1;
    const int l15 = lane & 15, kg = lane >> 4;
    const int y = blockIdx.x, b = blockIdx.y;

    for (int h = 0; h < 2; ++h) {
        const u16* gb = y1p + (size_t)h * 8388608 + ((size_t)b * 128 + y) * 16384;
        for (int iss = wave; iss < 32; iss += 4)
            gld_lds16((const char*)gb + iss * 1024 + lane * 16,
                      smem + h * 32768 + iss * 1024);
    }
    asm volatile("s_waitcnt vmcnt(0)" ::: "memory");
    __syncthreads();

    f32x4 accL[4][4];
#pragma unroll
    for (int fm = 0; fm < 4; ++fm)
#pragma unroll
        for (int fn = 0; fn < 4; ++fn)
#pragma unroll
            for (int j = 0; j < 4; ++j) accL[fm][fn][j] = 0.0f;

    const float* xb = input + (size_t)b * CI * PP;

    for (int tap = 0; tap < 9; ++tap) {
        const int ry  = y + tap / 3 - 1;
        const int dxo = tap % 3 - 1;
        if ((unsigned)ry >= (unsigned)HH) continue;   // wave-uniform: x==0 rows

        f32x4 accG[4][4];
#pragma unroll
        for (int fm = 0; fm < 4; ++fm) {
            float bv[4];
#pragma unroll
            for (int j = 0; j < 4; ++j)
                bv[j] = b12[(wm * 64 + fm * 16 + kg * 4 + j) * 9 + tap];
#pragma unroll
            for (int fn = 0; fn < 4; ++fn)
#pragma unroll
                for (int j = 0; j < 4; ++j) accG[fm][fn][j] = bv[j];
        }

#pragma unroll
        for (int ks = 0; ks < 4; ++ks) {
            bf16x8 bh[4], bl[4];
#pragma unroll
            for (int f = 0; f < 4; ++f) {
                const int px = wn * 64 + f * 16 + l15;
                const u32 bo = swz((u32)(px * 256 + ks * 64 + kg * 16));
                bh[f] = *(const bf16x8*)(smem + bo);
                bl[f] = *(const bf16x8*)(smem + 32768 + bo);
            }
#pragma unroll
            for (int fm = 0; fm < 4; ++fm) {
                const size_t ao = ((size_t)(tap * 128 + wm * 64 + fm * 16 + l15)) * 128
                                  + ks * 32 + kg * 8;
                const bf16x8 ah = *(const bf16x8*)(w12p + ao);
                const bf16x8 al = *(const bf16x8*)(w12p + 147456 + ao);
#pragma unroll
                for (int fn = 0; fn < 4; ++fn) {
                    accG[fm][fn] = __builtin_amdgcn_mfma_f32_16x16x32_bf16(
                        al, bh[fn], accG[fm][fn], 0, 0, 0);
                    accG[fm][fn] = __builtin_amdgcn_mfma_f32_16x16x32_bf16(
                        ah, bl[fn], accG[fm][fn], 0, 0, 0);
                    accG[fm][fn] = __builtin_amdgcn_mfma_f32_16x16x32_bf16(
                        ah, bh[fn], accG[fm][fn], 0, 0, 0);
                }
            }
        }

        // fold: accL += G_k * x[ci][ry][px+dxo]
#pragma unroll
        for (int fm = 0; fm < 4; ++fm)
#pragma unroll
            for (int fn = 0; fn < 4; ++fn) {
                const int px = wn * 64 + fn * 16 + l15;
                const int rx = px + dxo;
                const bool okx = (unsigned)rx < (unsigned)WW;
                const float* xr = xb + (size_t)ry * WW + (okx ? rx : 0);
#pragma unroll
                for (int j = 0; j < 4; ++j) {
                    const int ci = wm * 64 + fm * 16 + kg * 4 + j;
                    const float xv = okx ? xr[(size_t)ci * PP] : 0.0f;
                    accL[fm][fn][j] = fmaf(accG[fm][fn][j], xv, accL[fm][fn][j]);
                }
            }
    }

    // epilogue: BN1 + ReLU + split -> swizzled image -> coalesced store
    __syncthreads();
    u16* img = (u16*)smem;
#pragma unroll
    for (int fm = 0; fm < 4; ++fm) {
        float sc[4], sh[4];
#pragma unroll
        for (int j = 0; j < 4; ++j) {
            const int cc = wm * 64 + fm * 16 + kg * 4 + j;
            sc[j] = g1[cc] * rsqrtf(v1[cc] + EPSN);
            sh[j] = be1[cc] - m1[cc] * sc[j];
        }
#pragma unroll
        for (int fn = 0; fn < 4; ++fn) {
            const int px = wn * 64 + fn * 16 + l15;
            const int c0 = wm * 64 + fm * 16 + kg * 4;
            u16 hh[4], ll[4];
#pragma unroll
            for (int j = 0; j < 4; ++j) {
                const float v = fmaxf(fmaf(accL[fm][fn][j], sc[j], sh[j]), 0.0f);
                const u16 h = f2bf(v);
                hh[j] = h; ll[j] = f2bf(v - bf2f(h));
            }
            const u32 off = swz((u32)(px * 256 + c0 * 2));
            uint2 vh, vl;
            vh.x = (u32)hh[0] | ((u32)hh[1] << 16); vh.y = (u32)hh[2] | ((u32)hh[3] << 16);
            vl.x = (u32)ll[0] | ((u32)ll[1] << 16); vl.y = (u32)ll[2] | ((u32)ll[3] << 16);
            *(uint2*)((char*)img + off)         = vh;
            *(uint2*)((char*)img + 32768 + off) = vl;
        }
    }
    __syncthreads();
    for (int h = 0; h < 2; ++h) {
        uint4* gd = (uint4*)(locp + (size_t)h * 8388608 + ((size_t)b * 128 + y) * 16384);
        const uint4* s4 = (const uint4*)(smem + h * 32768);
        for (int i = t; i < 2048; i += 256) gd[i] = s4[i];
    }
}

// ---------------------------------------------------------------------------
// K5: channel-mix bmm via MFMA + BN2 + ReLU -> xpad3 interior (padded NHWC)
// ---------------------------------------------------------------------------
__global__ __launch_bounds__(256, 2) void k_bmm_mfma(
    const u16* __restrict__ locp, const u16* __restrict__ w22p,
    const float* __restrict__ g2, const float* __restrict__ be2,
    const float* __restrict__ m2, const float* __restrict__ v2,
    u16* __restrict__ x3h, u16* __restrict__ x3l)
{
    __shared__ char smem[65536];
    const int t = threadIdx.x;
    const int wave = t >> 6, lane = t & 63;
    const int wm = wave >> 1, wn = wave & 1;
    const int l15 = lane & 15, kg = lane >> 4;
    const int y = blockIdx.x, b = blockIdx.y;

    for (int h = 0; h < 2; ++h) {
        const u16* gb = locp + (size_t)h * 8388608 + ((size_t)b * 128 + y) * 16384;
        for (int iss = wave; iss < 32; iss += 4)
            gld_lds16((const char*)gb + iss * 1024 + lane * 16,
                      smem + h * 32768 + iss * 1024);
    }
    asm volatile("s_waitcnt vmcnt(0)" ::: "memory");
    __syncthreads();

    f32x4 acc[4][4];
#pragma unroll
    for (int fm = 0; fm < 4; ++fm)
#pragma unroll
        for (int fn = 0; fn < 4; ++fn)
#pragma unroll
            for (int j = 0; j < 4; ++j) acc[fm][fn][j] = 0.0f;

#pragma unroll
    for (int ks = 0; ks < 4; ++ks) {
        bf16x8 bh[4], bl[4];
#pragma unroll
        for (int f = 0; f < 4; ++f) {
            const int px = wn * 64 + f * 16 + l15;
            const u32 bo = swz((u32)(px * 256 + ks * 64 + kg * 16));
            bh[f] = *(const bf16x8*)(smem + bo);
            bl[f] = *(const bf16x8*)(smem + 32768 + bo);
        }
#pragma unroll
        for (int fm = 0; fm < 4; ++fm) {
            const size_t ao = ((size_t)(b * 128 + wm * 64 + fm * 16 + l15)) * 128
                              + ks * 32 + kg * 8;
            const bf16x8 ah = *(const bf16x8*)(w22p + ao);
            const bf16x8 al = *(const bf16x8*)(w22p + 65536 + ao);
#pragma unroll
            for (int fn = 0; fn < 4; ++fn) {
                acc[fm][fn] = __builtin_amdgcn_mfma_f32_16x16x32_bf16(
                    al, bh[fn], acc[fm][fn], 0, 0, 0);
                acc[fm][fn] = __builtin_amdgcn_mfma_f32_16x16x32_bf16(
                    ah, bl[fn], acc[fm][fn], 0, 0, 0);
                acc[fm][fn] = __builtin_amdgcn_mfma_f32_16x16x32_bf16(
                    ah, bh[fn], acc[fm][fn], 0, 0, 0);
            }
        }
    }

    __syncthreads();
    u16* img = (u16*)smem;   // LINEAR [px][c] (conv3 staging expects linear)
#pragma unroll
    for (int fm = 0; fm < 4; ++fm) {
        float sc[4], sh[4];
#pragma unroll
        for (int j = 0; j < 4; ++j) {
            const int cc = wm * 64 + fm * 16 + kg * 4 + j;
            sc[j] = g2[cc] * rsqrtf(v2[cc] + EPSN);
            sh[j] = be2[cc] - m2[cc] * sc[j];
        }
#pragma unroll
        for (int fn = 0; fn < 4; ++fn) {
            const int px = wn * 64 + fn * 16 + l15;
            const int c0 = wm * 64 + fm * 16 + kg * 4;
            u16 hh[4], ll[4];
#pragma unroll
            for (int j = 0; j < 4; ++j) {
                const float v = fmaxf(fmaf(acc[fm][fn][j], sc[j], sh[j]), 0.0f);
                const u16 h = f2bf(v);
                hh[j] = h; ll[j] = f2bf(v - bf2f(h));
            }
            const u32 off = (u32)(px * 256 + c0 * 2);
            uint2 vh, vl;
            vh.x = (u32)hh[0] | ((u32)hh[1] << 16); vh.y = (u32)hh[2] | ((u32)hh[3] << 16);
            vl.x = (u32)ll[0] | ((u32)ll[1] << 16); vl.y = (u32)ll[2] | ((u32)ll[3] << 16);
            *(uint2*)((char*)img + off)         = vh;
            *(uint2*)((char*)img + 32768 + off) = vl;
        }
    }
    __syncthreads();
    for (int h = 0; h < 2; ++h) {
        uint4* gd = (uint4*)((h ? x3l : x3h)
            + (((size_t)b * 130 + y + 1) * 130 + 1) * 128);
        const uint4* s4 = (const uint4*)(smem + h * 32768);
        for (int i = t; i < 2048; i += 256) gd[i] = s4[i];
    }
}

// ---------------------------------------------------------------------------
// K5b: zero the halo borders of xpad3 (rows 0/129, cols 0/129).
// ---------------------------------------------------------------------------
__global__ __launch_bounds__(256) void k_zero3(u16* __restrict__ x3)
{
    const int idx = blockIdx.x * 256 + threadIdx.x;
    if (idx >= 264192) return;                    // total u32 stores
    const int hb = idx / 33024;                   // h*4+b
    int r2 = idx % 33024;
    u32* base = (u32*)(x3 + (size_t)(hb >> 2) * 8652800
                          + (size_t)(hb & 3) * 130 * 130 * 128);
    if (r2 < 8320)            base[r2] = 0u;                              // row 0
    else if (r2 < 16640)      base[(size_t)129 * 8320 + (r2 - 8320)] = 0u; // row 129
    else {
        const int q = r2 - 16640;                 // 128 rows x 2 sides x 64 u32
        const int w = q & 63;
        const int r = q >> 6;
        const int row = 1 + (r >> 1);
        const int side = r & 1;
        base[(size_t)row * 8320 + (side ? 8256 : 0) + w] = 0u;
    }
}

// ---------------------------------------------------------------------------
extern "C" void kernel_launch(void* const* d_in, const int* in_sizes, int n_in,
                              void* d_out, int out_size, void* d_ws, size_t ws_size,
                              hipStream_t stream)
{
    (void)in_sizes; (void)n_in; (void)out_size; (void)ws_size;

    const float* input  = (const float*)d_in[0];
    const float* weight = (const float*)d_in[1];
    const float* w11    = (const float*)d_in[2];
    const float* b11    = (const float*)d_in[3];
    const float* w12    = (const float*)d_in[4];
    const float* b12    = (const float*)d_in[5];
    const float* w21    = (const float*)d_in[6];
    const float* b21    = (const float*)d_in[7];
    const float* w22    = (const float*)d_in[8];
    const float* b22    = (const float*)d_in[9];
    const float* g1     = (const float*)d_in[10];
    const float* be1    = (const float*)d_in[11];
    const float* m1     = (const float*)d_in[12];
    const float* v1     = (const float*)d_in[13];
    const float* g2     = (const float*)d_in[14];
    const float* be2    = (const float*)d_in[15];
    const float* m2     = (const float*)d_in[16];
    const float* v2     = (const float*)d_in[17];
    const float* w3     = (const float*)d_in[18];
    const float* g3     = (const float*)d_in[19];
    const float* be3    = (const float*)d_in[20];
    const float* m3     = (const float*)d_in[21];
    const float* v3     = (const float*)d_in[22];

    // Workspace layout (float offsets), total 30823936 floats = 123.3MB:
    //  y2o 0 (+8388608) | pooled 8388608 (+512) | w22p 8389120 (+65536)
    //  wAd 8454656 (+442368) | wA3 8897024 (+147456) | w12p 9044480 (+147456)
    //  G 9191936 (+12979200): xpadD (dead after conv_dual); locp aliases G
    //  H 22171136 (+8652800): y1p (dead after guided) then xpad3
    float* ws     = (float*)d_ws;
    float* y2o    = ws;
    float* pooled = ws + 8388608;
    u16*   w22p   = (u16*)(ws + 8389120);
    u16*   wAd    = (u16*)(ws + 8454656);
    u16*   wA3    = (u16*)(ws + 8897024);
    u16*   w12p   = (u16*)(ws + 9044480);
    u16*   xpadDh = (u16*)(ws + 9191936);
    u16*   xpadDl = xpadDh + 12979200;         // 4*130*130*192 per half
    u16*   locp   = (u16*)(ws + 9191936);      // aliases xpadD (dead)
    u16*   y1p    = (u16*)(ws + 22171136);
    u16*   x3h    = (u16*)(ws + 22171136);     // aliases y1p (dead)
    u16*   x3l    = x3h + 8652800;             // 4*130*130*128 per half
    float* outp   = (float*)d_out;

    k_pack<<<dim3(130, BB), 256, 0, stream>>>(input, CI, weight, CG, xpadDh, xpadDl, CIN);
    k_wpack<<<dim3(216), 256, 0, stream>>>(w11, w21, wAd, 2, 6, CIN);
    k_wpack<<<dim3(72), 256, 0, stream>>>(w3, w3, wA3, 1, 4, CI);
    k_wpack12<<<dim3(72), 256, 0, stream>>>(w12, w12p);

    k_conv_mfma<6, true><<<dim3(128, 2, BB), 256, 0, stream>>>(
        xpadDh, xpadDl, wAd, b11, b21, nullptr, nullptr, nullptr, nullptr,
        nullptr, y2o, y1p, y1p + 8388608);

    k_pool<<<dim3(CI, BB), 256, 0, stream>>>(y2o, pooled);
    k_w22<<<dim3(64, BB), 256, 0, stream>>>(w22, b22, pooled, w22p);

    k_guided_mfma<<<dim3(128, BB), 256, 0, stream>>>(
        input, y1p, w12p, b12, g1, be1, m1, v1, locp);

    k_zero3<<<dim3(1032), 256, 0, stream>>>(x3h);

    k_bmm_mfma<<<dim3(128, BB), 256, 0, stream>>>(
        locp, w22p, g2, be2, m2, v2, x3h, x3l);

    k_conv_mfma<4, false><<<dim3(128, 1, BB), 256, 0, stream>>>(
        x3h, x3l, wA3, nullptr, nullptr, g3, be3, m3, v3, outp, nullptr,
        nullptr, nullptr);
}